// Round 1
// baseline (404.172 us; speedup 1.0000x reference)
//
#include <hip/hip_runtime.h>
#include <math.h>

#define NN    50000
#define NE    1600000
#define INDIM 2000
#define HID   8

// ---------------- degree / normalization ----------------

__global__ __launch_bounds__(256) void k_deg_init(float* __restrict__ deg, int n) {
    int i = blockIdx.x * 256 + threadIdx.x;
    if (i < n) deg[i] = 1.0f;   // self-loop weight 1
}

__global__ __launch_bounds__(256) void k_deg_scatter(const int* __restrict__ dst,
                                                     const float* __restrict__ w,
                                                     float* __restrict__ deg, int e) {
    int i = blockIdx.x * 256 + threadIdx.x;
    if (i < e) atomicAdd(&deg[dst[i]], w[i]);
}

// wd[e] = w[e] * dinv[dst[e]]   (shared by both conv layers)
__global__ __launch_bounds__(256) void k_wd(const int* __restrict__ dst,
                                            const float* __restrict__ w,
                                            const float* __restrict__ deg,
                                            float* __restrict__ wd, int e) {
    int i = blockIdx.x * 256 + threadIdx.x;
    if (i < e) wd[i] = w[i] * rsqrtf(deg[dst[i]]);
}

// ---------------- layer 1 GEMM: g1 = dinv * (x @ W1), agg1 = dinv * g1 ----------------
// one wave -> 4 rows; W1 transposed in LDS; float4 x loads; butterfly reduce.

__global__ __launch_bounds__(256) void k_gemm1(const float* __restrict__ x,
                                               const float* __restrict__ W1,
                                               const float* __restrict__ deg,
                                               float* __restrict__ g1,
                                               float* __restrict__ agg1, int n) {
    __shared__ float Wt[HID][INDIM];   // 64000 B
    for (int idx = threadIdx.x; idx < INDIM * HID; idx += 256) {
        int c = idx >> 3, j = idx & 7;
        Wt[j][c] = W1[idx];
    }
    __syncthreads();

    const int wave = threadIdx.x >> 6;
    const int lane = threadIdx.x & 63;
    const int row0 = (blockIdx.x * 4 + wave) * 4;   // grid sized so row0+3 < n exactly

    float acc[4][HID];
#pragma unroll
    for (int r = 0; r < 4; ++r)
#pragma unroll
        for (int j = 0; j < HID; ++j) acc[r][j] = 0.0f;

#pragma unroll
    for (int k = 0; k < 8; ++k) {
        int c = k * 256 + lane * 4;
        if (c < INDIM) {
            float4 wv[HID];
#pragma unroll
            for (int j = 0; j < HID; ++j)
                wv[j] = *(const float4*)&Wt[j][c];
#pragma unroll
            for (int r = 0; r < 4; ++r) {
                const float4 xv = *(const float4*)&x[(size_t)(row0 + r) * INDIM + c];
#pragma unroll
                for (int j = 0; j < HID; ++j)
                    acc[r][j] += xv.x * wv[j].x + xv.y * wv[j].y +
                                 xv.z * wv[j].z + xv.w * wv[j].w;
            }
        }
    }

    // full-wave butterfly reduction: every lane ends with the complete sums
#pragma unroll
    for (int off = 32; off >= 1; off >>= 1) {
#pragma unroll
        for (int r = 0; r < 4; ++r)
#pragma unroll
            for (int j = 0; j < HID; ++j)
                acc[r][j] += __shfl_xor(acc[r][j], off);
    }

    if (lane < 4) {
        const int row = row0 + lane;
        const float di = rsqrtf(deg[row]);
        float4 a, b, sa, sb;
        a.x = di * acc[lane][0]; a.y = di * acc[lane][1];
        a.z = di * acc[lane][2]; a.w = di * acc[lane][3];
        b.x = di * acc[lane][4]; b.y = di * acc[lane][5];
        b.z = di * acc[lane][6]; b.w = di * acc[lane][7];
        sa.x = di * a.x; sa.y = di * a.y; sa.z = di * a.z; sa.w = di * a.w;
        sb.x = di * b.x; sb.y = di * b.y; sb.z = di * b.z; sb.w = di * b.w;
        *(float4*)&g1[(size_t)row * HID]       = a;
        *(float4*)&g1[(size_t)row * HID + 4]   = b;
        *(float4*)&agg1[(size_t)row * HID]     = sa;  // self-loop contribution
        *(float4*)&agg1[(size_t)row * HID + 4] = sb;
    }
}

// ---------------- message passing: agg[dst,ch] += wd[e] * g[src,ch] ----------------
// thread = (edge, channel): 8 lanes share edge metadata, gather 32B contiguous.

__global__ __launch_bounds__(256) void k_scatter(const int* __restrict__ src,
                                                 const int* __restrict__ dst,
                                                 const float* __restrict__ wd,
                                                 const float* __restrict__ g,
                                                 float* __restrict__ agg, int e) {
    int t = blockIdx.x * 256 + threadIdx.x;
    int eid = t >> 3, ch = t & 7;
    if (eid < e) {
        int s = src[eid], d = dst[eid];
        float v = wd[eid] * g[s * HID + ch];
        atomicAdd(&agg[d * HID + ch], v);
    }
}

// ---------------- layer 2 transform: t = relu(agg1+b1); h2 = t@W2; ----------------
// g2 = dinv*h2 (reuses g buffer);  out(=agg2 init) = dinv*g2

__global__ __launch_bounds__(256) void k_transform2(const float* __restrict__ agg1,
                                                    const float* __restrict__ b1,
                                                    const float* __restrict__ W2,
                                                    const float* __restrict__ deg,
                                                    float* __restrict__ g2,
                                                    float* __restrict__ out, int n) {
    __shared__ float sW[HID * HID];
    __shared__ float sb[HID];
    if (threadIdx.x < HID * HID) sW[threadIdx.x] = W2[threadIdx.x];
    if (threadIdx.x < HID) sb[threadIdx.x] = b1[threadIdx.x];
    __syncthreads();

    int i = blockIdx.x * 256 + threadIdx.x;
    if (i < n) {
        float4 a = *(const float4*)&agg1[(size_t)i * HID];
        float4 b = *(const float4*)&agg1[(size_t)i * HID + 4];
        float t[HID] = { fmaxf(a.x + sb[0], 0.f), fmaxf(a.y + sb[1], 0.f),
                         fmaxf(a.z + sb[2], 0.f), fmaxf(a.w + sb[3], 0.f),
                         fmaxf(b.x + sb[4], 0.f), fmaxf(b.y + sb[5], 0.f),
                         fmaxf(b.z + sb[6], 0.f), fmaxf(b.w + sb[7], 0.f) };
        float h[HID];
#pragma unroll
        for (int j = 0; j < HID; ++j) {
            float s = 0.f;
#pragma unroll
            for (int k = 0; k < HID; ++k) s += t[k] * sW[k * HID + j];
            h[j] = s;
        }
        const float di = rsqrtf(deg[i]);
        float4 ga, gb, oa, ob;
        ga.x = di * h[0]; ga.y = di * h[1]; ga.z = di * h[2]; ga.w = di * h[3];
        gb.x = di * h[4]; gb.y = di * h[5]; gb.z = di * h[6]; gb.w = di * h[7];
        oa.x = di * ga.x; oa.y = di * ga.y; oa.z = di * ga.z; oa.w = di * ga.w;
        ob.x = di * gb.x; ob.y = di * gb.y; ob.z = di * gb.z; ob.w = di * gb.w;
        *(float4*)&g2[(size_t)i * HID]      = ga;
        *(float4*)&g2[(size_t)i * HID + 4]  = gb;
        *(float4*)&out[(size_t)i * HID]     = oa;   // self-loop init of agg2
        *(float4*)&out[(size_t)i * HID + 4] = ob;
    }
}

// ---------------- finalize: out = log_softmax(out + b2) in place ----------------

__global__ __launch_bounds__(256) void k_finalize(float* __restrict__ out,
                                                  const float* __restrict__ b2, int n) {
    __shared__ float sb[HID];
    if (threadIdx.x < HID) sb[threadIdx.x] = b2[threadIdx.x];
    __syncthreads();
    int i = blockIdx.x * 256 + threadIdx.x;
    if (i < n) {
        float v[HID];
        float4 a = *(const float4*)&out[(size_t)i * HID];
        float4 b = *(const float4*)&out[(size_t)i * HID + 4];
        v[0] = a.x + sb[0]; v[1] = a.y + sb[1]; v[2] = a.z + sb[2]; v[3] = a.w + sb[3];
        v[4] = b.x + sb[4]; v[5] = b.y + sb[5]; v[6] = b.z + sb[6]; v[7] = b.w + sb[7];
        float m = v[0];
#pragma unroll
        for (int j = 1; j < HID; ++j) m = fmaxf(m, v[j]);
        float s = 0.f;
#pragma unroll
        for (int j = 0; j < HID; ++j) s += expf(v[j] - m);
        const float ls = m + logf(s);
        float4 oa, ob;
        oa.x = v[0] - ls; oa.y = v[1] - ls; oa.z = v[2] - ls; oa.w = v[3] - ls;
        ob.x = v[4] - ls; ob.y = v[5] - ls; ob.z = v[6] - ls; ob.w = v[7] - ls;
        *(float4*)&out[(size_t)i * HID]     = oa;
        *(float4*)&out[(size_t)i * HID + 4] = ob;
    }
}

// ---------------- launcher ----------------

extern "C" void kernel_launch(void* const* d_in, const int* in_sizes, int n_in,
                              void* d_out, int out_size, void* d_ws, size_t ws_size,
                              hipStream_t stream) {
    const float* x  = (const float*)d_in[0];
    const int*   src = (const int*)d_in[1];
    const int*   dst = (const int*)d_in[2];
    const float* ew  = (const float*)d_in[3];
    const float* W1  = (const float*)d_in[4];
    const float* b1  = (const float*)d_in[5];
    const float* W2  = (const float*)d_in[6];
    const float* b2  = (const float*)d_in[7];
    float* out = (float*)d_out;

    // workspace layout (floats)
    float* ws   = (float*)d_ws;
    float* deg  = ws;                       // NN
    float* wd   = deg + NN;                 // NE
    float* g    = wd + NE;                  // NN*HID  (g1, then reused as g2)
    float* agg1 = g + (size_t)NN * HID;     // NN*HID

    const int B = 256;
    const int gN  = (NN + B - 1) / B;           // 196
    const int gE  = (NE + B - 1) / B;           // 6250
    const int gEC = (NE * HID + B - 1) / B;     // 50000
    const int gG  = NN / 16;                    // 3125 (exact: 16 rows/block)

    k_deg_init<<<gN, B, 0, stream>>>(deg, NN);
    k_deg_scatter<<<gE, B, 0, stream>>>(dst, ew, deg, NE);
    k_wd<<<gE, B, 0, stream>>>(dst, ew, deg, wd, NE);

    k_gemm1<<<gG, B, 0, stream>>>(x, W1, deg, g, agg1, NN);
    k_scatter<<<gEC, B, 0, stream>>>(src, dst, wd, g, agg1, NE);

    k_transform2<<<gN, B, 0, stream>>>(agg1, b1, W2, deg, g, out, NN);
    k_scatter<<<gEC, B, 0, stream>>>(src, dst, wd, g, out, NE);

    k_finalize<<<gN, B, 0, stream>>>(out, b2, NN);
}